// Round 12
// baseline (140.457 us; speedup 1.0000x reference)
//
#include <hip/hip_runtime.h>
#include <math.h>
#include <stdint.h>

#define T_TOK 8192
#define NEXP  256
#define HD    7168
#define PLANE ((size_t)T_TOK * NEXP)
#define SCALE 4096.0f
#define INV_S2 (1.0f / 16777216.0f)   // 2^-24
#define BM 256
#define BK 32                          // fp32 K-columns per step
#define NSTEP_TOT (HD / BK)            // 224
#define BIMG_STEP 32768                // bytes per K-step: 2 planes * 256 rows * 4 slots * 16B

typedef _Float16 h8  __attribute__((ext_vector_type(8)));
typedef float f32x16 __attribute__((ext_vector_type(16)));
typedef __attribute__((address_space(3))) uint8_t       lds_t;
typedef __attribute__((address_space(1))) const uint8_t gbl_t;

#define SB __builtin_amdgcn_sched_barrier(0);

// ---- W -> pre-swizzled f16 hi/lo LDS image [t][hl][row(256)][slot(4)] (16B chunks) ----
__global__ __launch_bounds__(256) void wconv(const float* __restrict__ W,
                                             _Float16* __restrict__ img) {
  const int cc  = blockIdx.x * 256 + threadIdx.x;
  const int t   = cc >> 11;
  const int c   = cc & 2047;
  const int hl  = c >> 10;
  const int rem = c & 1023;
  const int row = rem >> 2;
  const int sp  = rem & 3;
  const int sl  = sp ^ ((row >> 1) & 3);
  const int k   = t * BK + sl * 8;

  const float* src = W + (size_t)row * HD + k;
  const float4 v0 = *(const float4*)src;
  const float4 v1 = *(const float4*)(src + 4);
  const float xs[8] = {v0.x, v0.y, v0.z, v0.w, v1.x, v1.y, v1.z, v1.w};
  h8 out;
#pragma unroll
  for (int j = 0; j < 8; ++j) {
    const float v = xs[j] * SCALE;
    const _Float16 hh = (_Float16)v;
    out[j] = hl ? (_Float16)(v - (float)hh) : hh;
  }
  *(h8*)(img + (size_t)cc * 8) = out;
}

// ---- Router GEMM: 256x256, 8 waves (2Mx4N, 128x64), never-drain counted pipeline ----
__global__ __launch_bounds__(512, 2) void router_gemm(
    const float* __restrict__ X, const _Float16* __restrict__ img,
    float* __restrict__ partial, int S) {
  __shared__ __align__(1024) _Float16 As[2][2][BM][BK];    // 64 KB
  __shared__ __align__(1024) _Float16 Bs[2][2][NEXP][BK];  // 64 KB

  const int tid = threadIdx.x;
  const int id  = blockIdx.x;
  const int sb  = id % S;        // S=8: one K-slice per XCD, img slice L2-hot
  const int mb  = id / S;

  const int row0  = mb * BM;
  const int nstep = (HD / S) / BK;
  const int tbase = sb * nstep;

  const int lane = tid & 63, wv = tid >> 6;
  const int wm = wv >> 2, wn = wv & 3;        // wave tile 128(M) x 64(N)
  const int r31 = lane & 31, kg = lane >> 5;

  const int sm = tid >> 1;                    // A staging row 0..255
  const int sk = tid & 1;                     // 16-float half-row

  const float* Ap = X + (size_t)(row0 + sm) * HD + tbase * BK + sk * 16;
  const uint8_t* imgB = (const uint8_t*)img + (size_t)tbase * BIMG_STEP + tid * 16;

  f32x16 acc[4][2];
#pragma unroll
  for (int i = 0; i < 4; ++i)
#pragma unroll
    for (int j = 0; j < 2; ++j) acc[i][j] = (f32x16)(0.f);

#define LOAD_A(t)                                                              \
  {                                                                            \
    const float* ap = Ap + (size_t)(t) * BK;                                   \
    a0 = *(const float4*)(ap);                                                 \
    a1 = *(const float4*)(ap + 4);                                             \
    a2 = *(const float4*)(ap + 8);                                             \
    a3 = *(const float4*)(ap + 12);                                            \
  }

#define STAGE_B4(t, b)                                                         \
  {                                                                            \
    const uint8_t* g = imgB + (size_t)(t) * BIMG_STEP;                         \
    uint8_t* l = (uint8_t*)&Bs[b][0][0][0] + tid * 16;                         \
    _Pragma("unroll")                                                          \
    for (int i = 0; i < 4; ++i)                                                \
      __builtin_amdgcn_global_load_lds((gbl_t*)(uintptr_t)(g + i * 8192),      \
                                       (lds_t*)(uintptr_t)(l + i * 8192), 16, 0, 0); \
  }

#define CVT_WRITE_A(b)                                                         \
  {                                                                            \
    const float xs[16] = {a0.x, a0.y, a0.z, a0.w, a1.x, a1.y, a1.z, a1.w,      \
                          a2.x, a2.y, a2.z, a2.w, a3.x, a3.y, a3.z, a3.w};     \
    h8 hv0, hv1, lv0, lv1;                                                     \
    _Pragma("unroll")                                                          \
    for (int j = 0; j < 8; ++j) {                                              \
      const float v = xs[j] * SCALE;                                           \
      const _Float16 hh = (_Float16)v;                                         \
      hv0[j] = hh; lv0[j] = (_Float16)(v - (float)hh);                         \
    }                                                                          \
    _Pragma("unroll")                                                          \
    for (int j = 0; j < 8; ++j) {                                              \
      const float v = xs[8 + j] * SCALE;                                       \
      const _Float16 hh = (_Float16)v;                                         \
      hv1[j] = hh; lv1[j] = (_Float16)(v - (float)hh);                         \
    }                                                                          \
    const int s0 = (sk * 2) ^ ((sm >> 1) & 3);                                 \
    const int s1 = (sk * 2 + 1) ^ ((sm >> 1) & 3);                             \
    *(h8*)&As[b][0][sm][s0 * 8] = hv0;                                         \
    *(h8*)&As[b][0][sm][s1 * 8] = hv1;                                         \
    *(h8*)&As[b][1][sm][s0 * 8] = lv0;                                         \
    *(h8*)&As[b][1][sm][s1 * 8] = lv1;                                         \
  }

#define READ_B(ks, dst)                                                        \
  _Pragma("unroll")                                                            \
  for (int ni = 0; ni < 2; ++ni)                                               \
    _Pragma("unroll")                                                          \
    for (int pl = 0; pl < 2; ++pl) {                                           \
      const int col = wn * 64 + ni * 32 + r31;                                 \
      const int sp  = ((ks) * 2 + kg) ^ ((col >> 1) & 3);                      \
      dst[ni][pl] = *(const h8*)&Bs[cur][pl][col][sp * 8];                     \
    }

#define READ_A(ks, mbase, dst)                                                 \
  _Pragma("unroll")                                                            \
  for (int mi = 0; mi < 2; ++mi)                                               \
    _Pragma("unroll")                                                          \
    for (int pl = 0; pl < 2; ++pl) {                                           \
      const int row = wm * 128 + ((mbase) + mi) * 32 + r31;                    \
      const int sp  = ((ks) * 2 + kg) ^ ((row >> 1) & 3);                      \
      dst[mi][pl] = *(const h8*)&As[cur][pl][row][sp * 8];                     \
    }

#define MFMA12(aF, bF, mbase)                                                  \
  __builtin_amdgcn_s_setprio(1);                                               \
  _Pragma("unroll")                                                            \
  for (int mi = 0; mi < 2; ++mi)                                               \
    _Pragma("unroll")                                                          \
    for (int ni = 0; ni < 2; ++ni)                                             \
      acc[(mbase) + mi][ni] = __builtin_amdgcn_mfma_f32_32x32x16_f16(          \
          aF[mi][0], bF[ni][0], acc[(mbase) + mi][ni], 0, 0, 0);               \
  _Pragma("unroll")                                                            \
  for (int mi = 0; mi < 2; ++mi)                                               \
    _Pragma("unroll")                                                          \
    for (int ni = 0; ni < 2; ++ni)                                             \
      acc[(mbase) + mi][ni] = __builtin_amdgcn_mfma_f32_32x32x16_f16(          \
          aF[mi][1], bF[ni][0], acc[(mbase) + mi][ni], 0, 0, 0);               \
  _Pragma("unroll")                                                            \
  for (int mi = 0; mi < 2; ++mi)                                               \
    _Pragma("unroll")                                                          \
    for (int ni = 0; ni < 2; ++ni)                                             \
      acc[(mbase) + mi][ni] = __builtin_amdgcn_mfma_f32_32x32x16_f16(          \
          aF[mi][0], bF[ni][1], acc[(mbase) + mi][ni], 0, 0, 0);               \
  __builtin_amdgcn_s_setprio(0);

  // ---- prologue: A(0) regs -> cvt -> As[0]; B(0) DMA left IN FLIGHT ----
  {
    float4 a0, a1, a2, a3;
    LOAD_A(0); SB;
    STAGE_B4(0, 0); SB;
    asm volatile("s_waitcnt vmcnt(4)" ::: "memory"); SB;   // A(0) regs ready; B(0) rides
    CVT_WRITE_A(0);
  }

  for (int t = 0; t < nstep; ++t) {
    const int cur = t & 1;
    const int nxt = cur ^ 1;
    const bool more = (t + 1 < nstep);

    float4 a0, a1, a2, a3;
    h8 b0[2][2], b1[2][2], aP[2][2], aQ[2][2], aR[2][2], aS[2][2];

    // ---- TOP: issue A(t+1), counted-wait B(t), single barrier publishes both bufs ----
    if (more) { LOAD_A(t + 1); }
    SB;
    if (more) { asm volatile("s_waitcnt vmcnt(2) lgkmcnt(0)" ::: "memory"); }
    else      { asm volatile("s_waitcnt vmcnt(0) lgkmcnt(0)" ::: "memory"); }
    SB;
    __builtin_amdgcn_s_barrier();

    // ---- ds_read ks0 (12), ks1-B (4); issue B-DMA(t+1); counted lgkm waits ----
    READ_B(0, b0);
    READ_A(0, 0, aP);
    READ_A(0, 2, aQ);
    SB;
    READ_B(1, b1);
    SB;
    if (more) { STAGE_B4(t + 1, nxt); }
    SB;
    asm volatile("s_waitcnt lgkmcnt(4)" ::: "memory"); SB;   // ks0 frags done; b1 rides
    MFMA12(aP, b0, 0);
    SB;
    READ_A(1, 0, aR);
    READ_A(1, 2, aS);
    SB;
    MFMA12(aQ, b0, 2);
    SB;
    asm volatile("s_waitcnt lgkmcnt(4)" ::: "memory"); SB;   // b1 + aR done; aS rides
    MFMA12(aR, b1, 0);
    SB;
    if (more) {
      asm volatile("s_waitcnt vmcnt(4)" ::: "memory"); SB;   // A(t+1) regs done; B-DMA(t+1) rides
      CVT_WRITE_A(nxt);
      SB;
    }
    asm volatile("s_waitcnt lgkmcnt(4)" ::: "memory"); SB;   // aS done; A-writes ride
    MFMA12(aS, b1, 2);
  }

  // Epilogue. 32x32 C/D: col = lane&31, row = (reg&3) + 8*(reg>>2) + 4*(lane>>5)
  float* base = partial + (size_t)sb * PLANE;
#pragma unroll
  for (int mi = 0; mi < 4; ++mi)
#pragma unroll
    for (int ni = 0; ni < 2; ++ni) {
      const int col = wn * 64 + ni * 32 + r31;
#pragma unroll
      for (int reg = 0; reg < 16; ++reg) {
        const int rr  = (reg & 3) + 8 * (reg >> 2) + 4 * kg;
        const int row = row0 + wm * 128 + mi * 32 + rr;
        base[(size_t)row * NEXP + col] = acc[mi][ni][reg];
      }
    }
}

// ---------------- Gating: one wave per token; sums S partial planes ----------------
__global__ __launch_bounds__(256) void gate_kernel(const float* __restrict__ logits,
                                                   const float* __restrict__ bias,
                                                   float* __restrict__ out_w,
                                                   float* __restrict__ out_e, int S) {
    const int wave = threadIdx.x >> 6;
    const int lane = threadIdx.x & 63;
    const int t = blockIdx.x * 4 + wave;
    if (t >= T_TOK) return;

    float l4[4] = {0.f, 0.f, 0.f, 0.f};
    for (int s = 0; s < S; ++s) {  // fixed order -> deterministic
        const float4 v = *(const float4*)(&logits[(size_t)s * PLANE + (size_t)t * NEXP + lane * 4]);
        l4[0] += v.x; l4[1] += v.y; l4[2] += v.z; l4[3] += v.w;
    }
    const float4 bv = *(const float4*)(&bias[lane * 4]);

    float s4[4], c[4];
#pragma unroll
    for (int j = 0; j < 4; ++j) s4[j] = 1.f / (1.f + expf(-l4[j] * INV_S2));
    c[0] = s4[0] + bv.x;
    c[1] = s4[1] + bv.y;
    c[2] = s4[2] + bv.z;
    c[3] = s4[3] + bv.w;

    float a = fmaxf(c[0], c[1]), b = fminf(c[0], c[1]);
    float d = fmaxf(c[2], c[3]), e = fminf(c[2], c[3]);
    float m1 = fmaxf(a, d);
    float m2 = fmaxf(fminf(a, d), fmaxf(b, e));
#pragma unroll
    for (int off = 1; off < 8; off <<= 1) {
        const float o1 = __shfl_xor(m1, off);
        const float o2 = __shfl_xor(m2, off);
        const float n1 = fmaxf(m1, o1);
        const float n2 = fmaxf(fminf(m1, o1), fmaxf(m2, o2));
        m1 = n1; m2 = n2;
    }
    const float gs = m1 + m2;
    const int   g  = lane >> 3;

    int rank = 0;
#pragma unroll
    for (int gg = 0; gg < 8; ++gg) {
        const float og = __shfl(gs, gg * 8);
        rank += (og > gs) || (og == gs && gg < g);
    }
    const bool gsel = rank < 4;

    float v[4];
#pragma unroll
    for (int j = 0; j < 4; ++j) v[j] = gsel ? c[j] : 0.0f;

    float selw = 0.f;
    int   seli = 0;
    float wsum = 0.f;

#pragma unroll
    for (int k = 0; k < 8; ++k) {
        float bvv = v[0]; int bi = lane * 4; float br = s4[0];
#pragma unroll
        for (int j = 1; j < 4; ++j) {
            if (v[j] > bvv) { bvv = v[j]; bi = lane * 4 + j; br = s4[j]; }
        }
#pragma unroll
        for (int off = 32; off > 0; off >>= 1) {
            const float ov = __shfl_xor(bvv, off);
            const int   oi = __shfl_xor(bi, off);
            const float orr = __shfl_xor(br, off);
            if (ov > bvv || (ov == bvv && oi < bi)) { bvv = ov; bi = oi; br = orr; }
        }
        if (lane == k) { selw = br; seli = bi; }
        wsum += br;
        const int rem = bi - lane * 4;
#pragma unroll
        for (int j = 0; j < 4; ++j)
            if (rem == j) v[j] = -INFINITY;
    }

    if (lane < 8) {
        const float w = selw / (wsum + 1e-20f) * 2.5f;
        out_w[(size_t)t * 8 + lane] = w;
        out_e[(size_t)t * 8 + lane] = (float)seli;
    }
}

extern "C" void kernel_launch(void* const* d_in, const int* in_sizes, int n_in,
                              void* d_out, int out_size, void* d_ws, size_t ws_size,
                              hipStream_t stream) {
    const float* X    = (const float*)d_in[0];
    const float* W    = (const float*)d_in[1];
    const float* bias = (const float*)d_in[2];
    float* out = (float*)d_out;

    _Float16* img = (_Float16*)d_ws;
    const size_t woff = (size_t)NSTEP_TOT * BIMG_STEP;   // 7,340,032 B
    float* partial = (float*)((char*)d_ws + woff);

    int S = 1;
    if (ws_size >= woff + 8 * PLANE * sizeof(float)) S = 8;       // 256 blocks = 1/CU
    else if (ws_size >= woff + 4 * PLANE * sizeof(float)) S = 4;
    else if (ws_size >= woff + 2 * PLANE * sizeof(float)) S = 2;

    wconv<<<dim3(NSTEP_TOT * 2048 / 256), 256, 0, stream>>>(W, img);
    router_gemm<<<dim3((T_TOK / BM) * S), 512, 0, stream>>>(X, img, partial, S);
    gate_kernel<<<dim3(T_TOK / 4), 256, 0, stream>>>(partial, bias, out, out + (size_t)T_TOK * 8, S);
}